// Round 11
// baseline (273.273 us; speedup 1.0000x reference)
//
#include <hip/hip_runtime.h>

#define N_NODES 100000
#define N_EDGES 1000000
#define IN_CH 128
#define HID_CH 64
#define N_CLS 40

#define NBUCK 782              // ceil(100000 / 128) buckets of 128 target cols

static inline int cdiv(int a, int b) { return (a + b - 1) / b; }

using bf16x8 = __attribute__((ext_vector_type(8))) short;   // 8 bf16 (4 VGPRs)
using f32x4  = __attribute__((ext_vector_type(4))) float;   // MFMA accumulator

// RNE float->bf16 pack (a in low 16, b in high 16)
__device__ __forceinline__ unsigned pack_bf2(float a, float b) {
    unsigned ua = __float_as_uint(a), ub = __float_as_uint(b);
    ua += 0x7fffu + ((ua >> 16) & 1u);
    ub += 0x7fffu + ((ub >> 16) & 1u);
    return (ua >> 16) | (ub & 0xffff0000u);
}
__device__ __forceinline__ unsigned short bf16_of(float a) {
    unsigned ua = __float_as_uint(a);
    ua += 0x7fffu + ((ua >> 16) & 1u);
    return (unsigned short)(ua >> 16);
}
__device__ __forceinline__ float bf_lo(unsigned u) { return __uint_as_float(u << 16); }
__device__ __forceinline__ float bf_hi(unsigned u) { return __uint_as_float(u & 0xffff0000u); }

// ---------------- bucket partition (col >> 7), pass 1: counts ----------------

__global__ __launch_bounds__(256)
void bucket_count_kernel(const int* __restrict__ cols, int* __restrict__ gcount, int E) {
    __shared__ int hist[NBUCK];
    for (int i = threadIdx.x; i < NBUCK; i += 256) hist[i] = 0;
    __syncthreads();
    int per = (E + gridDim.x - 1) / gridDim.x;
    int s = blockIdx.x * per;
    int e = min(E, s + per);
    for (int j = s + threadIdx.x; j < e; j += 256)
        atomicAdd(&hist[cols[j] >> 7], 1);
    __syncthreads();
    for (int i = threadIdx.x; i < NBUCK; i += 256)
        if (hist[i]) atomicAdd(&gcount[i], hist[i]);
}

// ---------------- scan 782 bucket counts -> boff[NBUCK+1], gcursor; offsets[N]=E ----------------

__global__ __launch_bounds__(1024)
void scan_bucket_kernel(const int* __restrict__ gcount, int* __restrict__ boff,
                        int* __restrict__ gcursor, int* __restrict__ offsets) {
    __shared__ int part[1024];
    int t = threadIdx.x;
    part[t] = (t < NBUCK) ? gcount[t] : 0;
    __syncthreads();
    for (int off = 1; off < 1024; off <<= 1) {
        int v = (t >= off) ? part[t - off] : 0;
        __syncthreads();
        part[t] += v;
        __syncthreads();
    }
    int excl = (t > 0) ? part[t - 1] : 0;
    if (t < NBUCK) { boff[t] = excl; gcursor[t] = excl; }
    if (t == NBUCK) { boff[NBUCK] = excl; offsets[N_NODES] = excl; }
}

// ---------------- pass 2: scatter edges into bucket order, packed (row<<7 | col&127) ----------------

__global__ __launch_bounds__(256)
void bucket_scatter_kernel(const int* __restrict__ rows, const int* __restrict__ cols,
                           int* __restrict__ gcursor, int* __restrict__ pedge, int E) {
    __shared__ int cur[NBUCK];
    for (int i = threadIdx.x; i < NBUCK; i += 256) cur[i] = 0;
    __syncthreads();
    int per = (E + gridDim.x - 1) / gridDim.x;
    int s = blockIdx.x * per;
    int e = min(E, s + per);
    for (int j = s + threadIdx.x; j < e; j += 256)
        atomicAdd(&cur[cols[j] >> 7], 1);
    __syncthreads();
    for (int i = threadIdx.x; i < NBUCK; i += 256) {
        int h = cur[i];
        cur[i] = h ? atomicAdd(&gcursor[i], h) : 0;
    }
    __syncthreads();
    for (int j = s + threadIdx.x; j < e; j += 256) {
        int c = cols[j];
        int pos = atomicAdd(&cur[c >> 7], 1);     // LDS returning atomic
        pedge[pos] = (rows[j] << 7) | (c & 127);
    }
}

// ---------------- per-bucket counting sort -> srow (CSR), offsets, dinv ----------------

__global__ __launch_bounds__(256)
void bucket_sort_kernel(const int* __restrict__ boff, const int* __restrict__ pedge,
                        int* __restrict__ srow, int* __restrict__ offsets,
                        float* __restrict__ dinv) {
    __shared__ int cnt[128];
    __shared__ int scn[128];
    __shared__ int cur[128];
    int b = blockIdx.x, t = threadIdx.x;
    if (t < 128) cnt[t] = 0;
    __syncthreads();
    int e0 = boff[b], e1 = boff[b + 1];
    for (int j = e0 + t; j < e1; j += 256)
        atomicAdd(&cnt[pedge[j] & 127], 1);
    __syncthreads();
    if (t < 128) scn[t] = cnt[t];
    __syncthreads();
    for (int off = 1; off < 128; off <<= 1) {
        int v = 0;
        if (t < 128 && t >= off) v = scn[t - off];
        __syncthreads();
        if (t < 128) scn[t] += v;
        __syncthreads();
    }
    if (t < 128) {
        int excl = (t > 0) ? scn[t - 1] : 0;
        cur[t] = excl;
        int node = b * 128 + t;
        if (node < N_NODES) {
            offsets[node] = e0 + excl;
            dinv[node] = cnt[t] ? rsqrtf((float)cnt[t]) : 0.f;
        }
    }
    __syncthreads();
    for (int j = e0 + t; j < e1; j += 256) {
        int p = pedge[j];
        int pos = atomicAdd(&cur[p & 127], 1);
        srow[e0 + pos] = p >> 7;
    }
}

// ---------------- one-shot weight pre-pack: W -> bf16 transposed images ----------------
// wt1 [CT1=128][K1/2=64] dwords : c<64 -> w1_init col c, else w1_root col c-64
// wt2 [CT2=80][K2/2=32] dwords  : c<40 -> w2_init col c, else w2_root col c-40
// dword kp packs k=2kp (lo) and k=2kp+1 (hi), matching the MFMA k-pair layout.

__global__ __launch_bounds__(256)
void pack_w_kernel(const float* __restrict__ W1i, const float* __restrict__ W1r,
                   const float* __restrict__ W2i, const float* __restrict__ W2r,
                   unsigned* __restrict__ wt1, unsigned* __restrict__ wt2) {
    int i = blockIdx.x * 256 + threadIdx.x;
    if (i < 128 * 64) {
        int c = i >> 6, kp = i & 63;
        int k = kp * 2;
        float a, b;
        if (c < 64) { a = W1i[k * 64 + c];        b = W1i[(k + 1) * 64 + c]; }
        else        { a = W1r[k * 64 + (c - 64)]; b = W1r[(k + 1) * 64 + (c - 64)]; }
        wt1[i] = pack_bf2(a, b);
    } else {
        int j = i - 128 * 64;
        if (j < 80 * 32) {
            int c = j >> 5, kp = j & 31;
            int k = kp * 2;
            float a, b;
            if (c < 40) { a = W2i[k * 40 + c];        b = W2i[(k + 1) * 40 + c]; }
            else        { a = W2r[k * 40 + (c - 40)]; b = W2r[(k + 1) * 40 + (c - 40)]; }
            wt2[j] = pack_bf2(a, b);
        }
    }
}

// ---------------- LDS-free MFMA fused GEMM ----------------
//  Y1b = bf16(dinv[r] * (X@W1))  (u16 stores, pull-gather input)
//  Y2  = X@W2 + Bias             (f32)
// No __shared__, no barriers (round-10 lesson: the LDS round-trip cost more
// than the matmul). One wave = one 16-row strip. A-frag: per-lane f32 global
// reads of X (16 rows x 64B contiguous segments/instr, LLC-served) packed to
// bf16 in registers. B-frags: b128 global reads of the pre-packed bf16 W^T
// image (<=32 KB, L2-hot, read-only). A[m=lane&15][k=quad*8+j],
// C/D: col=lane&15, row=quad*4+reg (verified maps).

template<int K, int C1, int C2>
__launch_bounds__(256)
__global__ void gemm_mfma_direct_kernel(const float* __restrict__ X,
                                        const unsigned* __restrict__ WTG,
                                        const float* __restrict__ Bias,
                                        const float* __restrict__ dinv,
                                        unsigned short* __restrict__ Y1b, // bf16 [N][C1]
                                        float* __restrict__ Y2, int N) {
    constexpr int CT = C1 + C2;
    constexpr int NT = CT / 16;            // 16-col tiles: 8 (L1) / 5 (L2)
    constexpr int KS = K / 32;             // k-steps: 4 (L1) / 2 (L2)
    constexpr int KPI = K / 2;             // dwords per W^T image row
    static_assert(CT % 16 == 0 && K % 32 == 0, "shape");

    const int tid = threadIdx.x;
    const int wave = tid >> 6;
    const int lane = tid & 63;
    const int m = lane & 15;
    const int quad = lane >> 4;
    const int r0 = blockIdx.x * 64 + wave * 16;   // this wave's 16-row strip

    // A-source row for this lane (clamped: OOB rows only affect D rows >= N,
    // which are never stored)
    int arow = r0 + m;
    const float* xrow = X + (size_t)(arow < N ? arow : 0) * K;

    f32x4 acc[NT];
#pragma unroll
    for (int t = 0; t < NT; ++t) acc[t] = (f32x4){0.f, 0.f, 0.f, 0.f};

#pragma unroll
    for (int ks = 0; ks < KS; ++ks) {
        const float* xp = xrow + ks * 32 + quad * 8;
        float4 v0 = *reinterpret_cast<const float4*>(xp);
        float4 v1 = *reinterpret_cast<const float4*>(xp + 4);
        union { unsigned u[4]; bf16x8 v; } A;
        A.u[0] = pack_bf2(v0.x, v0.y);
        A.u[1] = pack_bf2(v0.z, v0.w);
        A.u[2] = pack_bf2(v1.x, v1.y);
        A.u[3] = pack_bf2(v1.z, v1.w);
#pragma unroll
        for (int t = 0; t < NT; ++t) {
            bf16x8 b = *reinterpret_cast<const bf16x8*>(&WTG[(t * 16 + m) * KPI + ks * 16 + quad * 4]);
            acc[t] = __builtin_amdgcn_mfma_f32_16x16x32_bf16(A.v, b, acc[t], 0, 0, 0);
        }
    }

    // epilogue: D[quad*4+reg][m] per tile
    float dr[4];
#pragma unroll
    for (int reg = 0; reg < 4; ++reg) {
        int r = r0 + quad * 4 + reg;
        dr[reg] = (r < N) ? dinv[r] : 0.f;
    }
#pragma unroll
    for (int t = 0; t < NT; ++t) {
        int c = t * 16 + m;
        float bias = (c >= C1) ? Bias[c - C1] : 0.f;
#pragma unroll
        for (int reg = 0; reg < 4; ++reg) {
            int r = r0 + quad * 4 + reg;
            if (r >= N) continue;
            float v = acc[t][reg];
            if (c < C1) {
                Y1b[(size_t)r * C1 + c] = bf16_of(v * dr[reg]);
            } else {
                Y2[(size_t)r * C2 + (c - C1)] = v + bias;
            }
        }
    }
}

// ---------------- pull aggregation over pre-scaled bf16 H ----------------
//  Y[node] = relu(Y[node] + dinv[node] * sum_e H[srow[e]])
// Edge loop unrolled x4 (MLP=4; latency-bound, round-8/9 lesson).

template<int C>
__launch_bounds__(256)
__global__ void pull_bf16_kernel(const int* __restrict__ offsets,
                                 const int* __restrict__ srow,
                                 const float* __restrict__ dinv,
                                 const unsigned* __restrict__ H,   // bf16 [N][C], pre-scaled
                                 float* __restrict__ Y, int N) {
    constexpr int TPE = C / 4;             // lanes per node, 4 bf16 (uint2) each
    constexpr int CH = C / 2;              // uints per row
    int gid = blockIdx.x * blockDim.x + threadIdx.x;
    int node = gid / TPE;
    int lane = gid - node * TPE;
    if (node >= N) return;

    int e0 = offsets[node];
    int e1 = offsets[node + 1];
    float dc = dinv[node];

    float4 acc = make_float4(0.f, 0.f, 0.f, 0.f);
    int j = e0;
    for (; j + 4 <= e1; j += 4) {
        int r0 = srow[j + 0];
        int r1 = srow[j + 1];
        int r2 = srow[j + 2];
        int r3 = srow[j + 3];
        uint2 u0 = *reinterpret_cast<const uint2*>(&H[(size_t)r0 * CH + lane * 2]);
        uint2 u1 = *reinterpret_cast<const uint2*>(&H[(size_t)r1 * CH + lane * 2]);
        uint2 u2 = *reinterpret_cast<const uint2*>(&H[(size_t)r2 * CH + lane * 2]);
        uint2 u3 = *reinterpret_cast<const uint2*>(&H[(size_t)r3 * CH + lane * 2]);
        acc.x += (bf_lo(u0.x) + bf_lo(u1.x)) + (bf_lo(u2.x) + bf_lo(u3.x));
        acc.y += (bf_hi(u0.x) + bf_hi(u1.x)) + (bf_hi(u2.x) + bf_hi(u3.x));
        acc.z += (bf_lo(u0.y) + bf_lo(u1.y)) + (bf_lo(u2.y) + bf_lo(u3.y));
        acc.w += (bf_hi(u0.y) + bf_hi(u1.y)) + (bf_hi(u2.y) + bf_hi(u3.y));
    }
    for (; j < e1; ++j) {
        int r = srow[j];
        uint2 u = *reinterpret_cast<const uint2*>(&H[(size_t)r * CH + lane * 2]);
        acc.x += bf_lo(u.x);
        acc.y += bf_hi(u.x);
        acc.z += bf_lo(u.y);
        acc.w += bf_hi(u.y);
    }

    float4* Y4 = reinterpret_cast<float4*>(Y);
    size_t yi = (size_t)node * TPE + lane;
    float4 y = Y4[yi];
    y.x = fmaxf(fmaf(dc, acc.x, y.x), 0.f);
    y.y = fmaxf(fmaf(dc, acc.y, y.y), 0.f);
    y.z = fmaxf(fmaf(dc, acc.z, y.z), 0.f);
    y.w = fmaxf(fmaf(dc, acc.w, y.w), 0.f);
    Y4[yi] = y;
}

// ---------------- launcher ----------------

extern "C" void kernel_launch(void* const* d_in, const int* in_sizes, int n_in,
                              void* d_out, int out_size, void* d_ws, size_t ws_size,
                              hipStream_t stream) {
    const float* x       = (const float*)d_in[0];
    const int*   eidx    = (const int*)d_in[1];
    const float* w1_init = (const float*)d_in[2];
    const float* w1_root = (const float*)d_in[3];
    const float* b1      = (const float*)d_in[4];
    const float* w2_init = (const float*)d_in[5];
    const float* w2_root = (const float*)d_in[6];
    const float* b2      = (const float*)d_in[7];
    float* out = (float*)d_out;

    const int* rows = eidx;                // edge_index[0] (source)
    const int* cols = eidx + N_EDGES;      // edge_index[1] (target)

    // workspace layout (4-byte units, 16B-aligned blocks)
    int* wsi = (int*)d_ws;
    int*      gcount  = wsi;                         //     784
    int*      boff    = wsi + 784;                   //     788 (NBUCK+1 = 783 used)
    int*      gcursor = wsi + 1572;                  //     788
    unsigned* wt1g    = (unsigned*)(wsi + 2360);     //   8,192  (bf16 W^T image, L1)
    unsigned* wt2g    = (unsigned*)(wsi + 10552);    //   2,560  (bf16 W^T image, L2)
    float*    dinv    = (float*)(wsi + 13112);       // 100,000
    int*      offsets = wsi + 113112;                // 100,004 (N_NODES+1 used)
    int*      srow    = wsi + 213116;                // 1,000,000
    unsigned* h0b     = (unsigned*)(wsi + 1213116);  // 3,200,000 uints (bf16 h, reused as h2b)
    int*      pedge   = wsi + 1213116;               // aliases h0b: dead before gemm L1
    float*    agg1    = (float*)(wsi + 4413116);     // 6,400,000
    unsigned* h2b     = h0b;
    // total 10,813,116 * 4 B = 43.3 MB

    // ---- graph prep: bucket partition -> sorted CSR + dinv; weight pre-pack ----
    hipMemsetAsync(gcount, 0, 784 * sizeof(int), stream);
    pack_w_kernel<<<cdiv(128 * 64 + 80 * 32, 256), 256, 0, stream>>>(
        w1_init, w1_root, w2_init, w2_root, wt1g, wt2g);
    bucket_count_kernel<<<128, 256, 0, stream>>>(cols, gcount, N_EDGES);
    scan_bucket_kernel<<<1, 1024, 0, stream>>>(gcount, boff, gcursor, offsets);
    bucket_scatter_kernel<<<128, 256, 0, stream>>>(rows, cols, gcursor, pedge, N_EDGES);
    bucket_sort_kernel<<<NBUCK, 256, 0, stream>>>(boff, pedge, srow, offsets, dinv);

    const int GGRID = cdiv(N_NODES, 64);   // 1563

    // ---- layer 1 ----
    gemm_mfma_direct_kernel<IN_CH, HID_CH, HID_CH><<<GGRID, 256, 0, stream>>>(
        x, wt1g, b1, dinv, (unsigned short*)h0b, agg1, N_NODES);
    pull_bf16_kernel<HID_CH><<<cdiv(N_NODES * (HID_CH / 4), 256), 256, 0, stream>>>(
        offsets, srow, dinv, h0b, agg1, N_NODES);

    // ---- layer 2 ----
    gemm_mfma_direct_kernel<HID_CH, N_CLS, N_CLS><<<GGRID, 256, 0, stream>>>(
        agg1, wt2g, b2, dinv, (unsigned short*)h2b, out, N_NODES);
    pull_bf16_kernel<N_CLS><<<cdiv(N_NODES * (N_CLS / 4), 256), 256, 0, stream>>>(
        offsets, srow, dinv, h2b, out, N_NODES);
}